// Round 2
// baseline (834.152 us; speedup 1.0000x reference)
//
#include <hip/hip_runtime.h>
#include <hip/hip_bf16.h>
#include <cstdint>
#include <cstddef>

// Problem dims (fixed by the reference)
#define T_STEPS 2048
#define BATCH   8
#define D_DIM   1024
#define M_ROWS  (T_STEPS * BATCH)   // 16384 rows of x
#define N_COLS  (2 * D_DIM)         // 2048: W_alpha rows ++ W_x rows
#define K_DIM   D_DIM               // 1024

// GEMM tiling
#define BM 128
#define BN 128
#define BK 32
#define LDSS 40   // padded LDS row stride (bf16 elems): 80 B -> 16B-aligned, 2-way bank alias only

typedef __bf16 bf16x8 __attribute__((ext_vector_type(8)));
typedef float  f32x4  __attribute__((ext_vector_type(4)));

__device__ __forceinline__ unsigned short f2bf_rne(float f) {
    union { float f; unsigned u; } c; c.f = f;
    unsigned u = c.u;
    u += 0x7fffu + ((u >> 16) & 1u);   // round-to-nearest-even (inputs are finite)
    return (unsigned short)(u >> 16);
}

__device__ __forceinline__ float sigmoid_f(float z) {
    return 1.0f / (1.0f + __expf(-z));
}

__device__ __forceinline__ float tanh_f(float z) {
    // tanh(z) = 1 - 2/(exp(2z)+1); saturates correctly for |z| large
    float e = __expf(2.0f * z);
    return 1.0f - 2.0f / (e + 1.0f);
}

// ---------------------------------------------------------------------------
// fp32 -> bf16 convert (vectorized x4)
// ---------------------------------------------------------------------------
__global__ void cvt_bf16_kernel(const float* __restrict__ src,
                                unsigned short* __restrict__ dst, int n4) {
    int i = blockIdx.x * blockDim.x + threadIdx.x;
    if (i >= n4) return;
    float4 v = reinterpret_cast<const float4*>(src)[i];
    ushort4 o;
    o.x = f2bf_rne(v.x); o.y = f2bf_rne(v.y);
    o.z = f2bf_rne(v.z); o.w = f2bf_rne(v.w);
    reinterpret_cast<ushort4*>(dst)[i] = o;
}

// ---------------------------------------------------------------------------
// Fused bf16 MFMA GEMM: out[m,n] = sum_k x[m,k] * Wc[n,k]
//   n <  1024 -> alpha_out[m,n]     = sigmoid(acc + b_alpha[n])
//   n >= 1024 -> wx_out[m,n-1024]   = acc + b[n-1024]
// Block: 256 thr = 4 waves; tile 128x128, BK=32; each wave 64x64 (4x4 MFMA tiles)
// ---------------------------------------------------------------------------
__global__ __launch_bounds__(256, 2)
void gemm_kernel(const unsigned short* __restrict__ A,   // [M][K] bf16 (x)
                 const unsigned short* __restrict__ Bm,  // [N][K] bf16 (W_alpha ++ W_x)
                 const float* __restrict__ b_alpha,      // [D]
                 const float* __restrict__ b_x,          // [D]
                 float* __restrict__ alpha_out,          // [M][D] fp32
                 float* __restrict__ wx_out)             // [M][D] fp32
{
    __shared__ unsigned short sA[BM * LDSS];
    __shared__ unsigned short sB[BN * LDSS];

    const int tid  = threadIdx.x;
    const int wave = tid >> 6;
    const int lane = tid & 63;
    const int bn   = blockIdx.x;            // 0..15  (N tiles)
    const int bm   = blockIdx.y;            // 0..127 (M tiles)
    const int rowBase = bm * BM;
    const int colBase = bn * BN;
    const int wr = (wave >> 1) * 64;        // wave row offset within tile
    const int wc = (wave & 1) * 64;         // wave col offset within tile

    // staging: each thread moves 16 B x 2 rows per matrix per k-step
    const int ldRow = tid >> 2;             // 0..63
    const int ldK   = (tid & 3) * 8;        // 0,8,16,24

    const int laneHi = lane >> 4;           // quad 0..3
    const int laneLo = lane & 15;

    f32x4 acc[4][4];
#pragma unroll
    for (int i = 0; i < 4; i++)
#pragma unroll
        for (int j = 0; j < 4; j++)
            acc[i][j] = (f32x4)(0.0f);

    for (int k0 = 0; k0 < K_DIM; k0 += BK) {
        __syncthreads();
#pragma unroll
        for (int p = 0; p < 2; ++p) {
            int r = ldRow + p * 64;
            const bf16x8* ga = reinterpret_cast<const bf16x8*>(
                A + (size_t)(rowBase + r) * K_DIM + k0 + ldK);
            *reinterpret_cast<bf16x8*>(&sA[r * LDSS + ldK]) = *ga;
            const bf16x8* gb = reinterpret_cast<const bf16x8*>(
                Bm + (size_t)(colBase + r) * K_DIM + k0 + ldK);
            *reinterpret_cast<bf16x8*>(&sB[r * LDSS + ldK]) = *gb;
        }
        __syncthreads();

        bf16x8 af[4], bfr[4];
#pragma unroll
        for (int i = 0; i < 4; i++) {
            int r = wr + i * 16 + laneLo;
            af[i] = *reinterpret_cast<const bf16x8*>(&sA[r * LDSS + laneHi * 8]);
        }
#pragma unroll
        for (int j = 0; j < 4; j++) {
            int c = wc + j * 16 + laneLo;
            bfr[j] = *reinterpret_cast<const bf16x8*>(&sB[c * LDSS + laneHi * 8]);
        }
#pragma unroll
        for (int i = 0; i < 4; i++)
#pragma unroll
            for (int j = 0; j < 4; j++)
                acc[i][j] = __builtin_amdgcn_mfma_f32_16x16x32_bf16(
                    af[i], bfr[j], acc[i][j], 0, 0, 0);
    }

    // Epilogue. C/D layout: col = lane&15, row = (lane>>4)*4 + reg  [m89/m91]
#pragma unroll
    for (int i = 0; i < 4; i++) {
        int row = rowBase + wr + i * 16 + laneHi * 4;
#pragma unroll
        for (int j = 0; j < 4; j++) {
            int col = colBase + wc + j * 16 + laneLo;
            if (col < D_DIM) {
                float bias = b_alpha[col];
#pragma unroll
                for (int r = 0; r < 4; r++) {
                    float z = acc[i][j][r] + bias;
                    alpha_out[(size_t)(row + r) * D_DIM + col] = sigmoid_f(z);
                }
            } else {
                int c2 = col - D_DIM;
                float bias = b_x[c2];
#pragma unroll
                for (int r = 0; r < 4; r++)
                    wx_out[(size_t)(row + r) * D_DIM + c2] = acc[i][j][r] + bias;
            }
        }
    }
}

// ---------------------------------------------------------------------------
// Sequential scan: 8192 independent recurrences (one per (b,e)), coalesced in e.
// Software-pipelined: rotating register buffers, prefetch depth PF.
// 64-thread blocks -> 128 blocks spread over 128 CUs (was 32 CUs).
// Prefetch past t=T-1 reads into the bf16-x workspace region (valid memory,
// values never consumed).
//   v = tanh(h + wx); h = a*h + (1-a)*v; out = h^2 * sigmoid(h); hout[t+1] = h
// ---------------------------------------------------------------------------
#define PF 16
__global__ __launch_bounds__(64)
void scan_kernel(const float* __restrict__ alpha,  // [T][B*D]
                 const float* __restrict__ wx,     // [T][B*D]
                 const float* __restrict__ h0,     // [B*D]
                 float* __restrict__ out,          // [T][B*D]
                 float* __restrict__ hout)         // [T+1][B*D]
{
    const int i = blockIdx.x * blockDim.x + threadIdx.x;   // 0..8191
    const int n = BATCH * D_DIM;
    float h = h0[i];
    hout[i] = h;

    float pa[PF], pw[PF];
#pragma unroll
    for (int q = 0; q < PF; ++q) {
        pa[q] = alpha[(size_t)q * n + i];
        pw[q] = wx[(size_t)q * n + i];
    }

    for (int t0 = 0; t0 < T_STEPS; t0 += PF) {
#pragma unroll
        for (int q = 0; q < PF; ++q) {
            const int t = t0 + q;
            float a = pa[q];
            float w = pw[q];
            // issue prefetch for t+PF immediately (always in-bounds of ws)
            {
                const size_t off = (size_t)(t + PF) * n + i;
                pa[q] = alpha[off];
                pw[q] = wx[off];
            }
            float v = tanh_f(h + w);
            h = a * h + (1.0f - a) * v;
            out[(size_t)t * n + i] = h * h * sigmoid_f(h);
            hout[(size_t)(t + 1) * n + i] = h;
        }
    }
}

// ---------------------------------------------------------------------------
extern "C" void kernel_launch(void* const* d_in, const int* in_sizes, int n_in,
                              void* d_out, int out_size, void* d_ws, size_t ws_size,
                              hipStream_t stream) {
    const float* x       = (const float*)d_in[0];  // [T,B,D]
    const float* h0      = (const float*)d_in[1];  // [B,D]
    const float* W_alpha = (const float*)d_in[2];  // [D,D]
    const float* b_alpha = (const float*)d_in[3];  // [D]
    const float* W_x     = (const float*)d_in[4];  // [D,D]
    const float* b       = (const float*)d_in[5];  // [D]

    float* out  = (float*)d_out;                              // [T,B,D]
    float* hout = out + (size_t)T_STEPS * BATCH * D_DIM;      // [T+1,B,D]

    // Workspace layout (164 MB total):
    //   alpha fp32 (64 MB) | wx fp32 (64 MB) | x bf16 (32 MB) | Wc bf16 (4 MB)
    // NOTE: scan prefetches up to PF timesteps past the end of alpha/wx;
    // those reads land in the following region (valid, values unused).
    float* ws_alpha = (float*)d_ws;
    float* ws_wx    = ws_alpha + (size_t)M_ROWS * D_DIM;
    unsigned short* ws_x = (unsigned short*)(ws_wx + (size_t)M_ROWS * D_DIM);
    unsigned short* ws_W = ws_x + (size_t)M_ROWS * K_DIM;

    // 1) convert x, W_alpha, W_x to bf16
    {
        int n4 = M_ROWS * K_DIM / 4;
        cvt_bf16_kernel<<<(n4 + 255) / 256, 256, 0, stream>>>(x, ws_x, n4);
    }
    {
        int n4 = D_DIM * K_DIM / 4;
        cvt_bf16_kernel<<<(n4 + 255) / 256, 256, 0, stream>>>(W_alpha, ws_W, n4);
        cvt_bf16_kernel<<<(n4 + 255) / 256, 256, 0, stream>>>(
            W_x, ws_W + (size_t)D_DIM * K_DIM, n4);
    }

    // 2) fused GEMM (N = 2048 covers both projections) + bias + sigmoid epilogue
    {
        dim3 grid(N_COLS / BN, M_ROWS / BM);   // (16, 128)
        gemm_kernel<<<grid, 256, 0, stream>>>(ws_x, ws_W, b_alpha, b,
                                              ws_alpha, ws_wx);
    }

    // 3) sequential scan over T, parallel over (b, e)
    scan_kernel<<<(BATCH * D_DIM) / 64, 64, 0, stream>>>(ws_alpha, ws_wx,
                                                         h0, out, hout);
}

// Round 4
// 477.514 us; speedup vs baseline: 1.7469x; 1.7469x over previous
//
#include <hip/hip_runtime.h>
#include <hip/hip_bf16.h>
#include <cstdint>
#include <cstddef>

// Problem dims (fixed by the reference)
#define T_STEPS 2048
#define BATCH   8
#define D_DIM   1024
#define M_ROWS  (T_STEPS * BATCH)   // 16384 rows of x
#define N_COLS  (2 * D_DIM)         // 2048: W_alpha rows ++ W_x rows
#define K_DIM   D_DIM               // 1024
#define NCH     (BATCH * D_DIM)     // 8192 independent recurrence channels

// GEMM tiling (m97 pattern: unpadded LDS, global_load_lds staging)
#define BM 128
#define BN 128
#define BK 32

typedef __bf16 bf16x8 __attribute__((ext_vector_type(8)));
typedef float  f32x4  __attribute__((ext_vector_type(4)));

__device__ __forceinline__ unsigned short f2bf_rne(float f) {
    union { float f; unsigned u; } c; c.f = f;
    unsigned u = c.u;
    u += 0x7fffu + ((u >> 16) & 1u);   // round-to-nearest-even (inputs finite)
    return (unsigned short)(u >> 16);
}

__device__ __forceinline__ float sigmoid_f(float z) {
    return 1.0f / (1.0f + __expf(-z));
}

__device__ __forceinline__ float tanh_f(float z) {
    float e = __expf(2.0f * z);
    return 1.0f - 2.0f / (e + 1.0f);
}

// async global -> LDS DMA, 16 B per lane; LDS dest = wave-uniform base + lane*16
__device__ __forceinline__ void glds16(const void* gptr, void* lptr) {
    __builtin_amdgcn_global_load_lds(
        (const __attribute__((address_space(1))) unsigned int*)gptr,
        (__attribute__((address_space(3))) unsigned int*)lptr,
        16, 0, 0);
}

// ---------------------------------------------------------------------------
// fp32 -> bf16 convert (vectorized x4)
// ---------------------------------------------------------------------------
__global__ void cvt_bf16_kernel(const float* __restrict__ src,
                                unsigned short* __restrict__ dst, int n4) {
    int i = blockIdx.x * blockDim.x + threadIdx.x;
    if (i >= n4) return;
    float4 v = reinterpret_cast<const float4*>(src)[i];
    ushort4 o;
    o.x = f2bf_rne(v.x); o.y = f2bf_rne(v.y);
    o.z = f2bf_rne(v.z); o.w = f2bf_rne(v.w);
    reinterpret_cast<ushort4*>(dst)[i] = o;
}

// ---------------------------------------------------------------------------
// Fused bf16 MFMA GEMM (m97 structure): out[m,n] = sum_k x[m,k] * Wc[n,k]
//   n <  1024 -> alpha_out[m,n]   = sigmoid(acc + b_alpha[n])
//   n >= 1024 -> wx_out[m,n-1024] = acc + b[n-1024]
// 256 thr = 4 waves; tile 128x128, BK=32; wave = 64x64 (4x4 MFMA tiles).
// Staging via global_load_lds width=16: wave w, instr p stages 16-row segment
// seg = w*2+p: lane l -> global row seg*16 + l/4, cols (l&3)*8..+7;
// LDS dest = seg*512 shorts + l*8 shorts  ==> row-major [128][32] unpadded.
// (Round-3 bug: base was seg*1024 shorts -> overran sA into sB -> NaN.)
// ---------------------------------------------------------------------------
__global__ __launch_bounds__(256, 2)
void gemm_kernel(const unsigned short* __restrict__ A,   // [M][K] bf16 (x)
                 const unsigned short* __restrict__ Bm,  // [N][K] bf16 (W_alpha ++ W_x)
                 const float* __restrict__ b_alpha,      // [D]
                 const float* __restrict__ b_x,          // [D]
                 float* __restrict__ alpha_out,          // [M][D] fp32
                 float* __restrict__ wx_out)             // [M][D] fp32
{
    __shared__ unsigned short sA[BM * BK];   // 8 KB
    __shared__ unsigned short sB[BN * BK];   // 8 KB

    const int tid  = threadIdx.x;
    const int wave = tid >> 6;
    const int lane = tid & 63;
    const int rowBase = blockIdx.y * BM;
    const int colBase = blockIdx.x * BN;
    const int wr = (wave >> 1) * 64;
    const int wc = (wave & 1) * 64;

    const int laneHi = lane >> 4;           // 0..3
    const int laneLo = lane & 15;

    // DMA staging addresses (per lane): row sub-offset + col offset
    const int dRow = lane >> 2;             // 0..15
    const int dCol = (lane & 3) * 8;        // 0,8,16,24

    f32x4 acc[4][4];
#pragma unroll
    for (int i = 0; i < 4; i++)
#pragma unroll
        for (int j = 0; j < 4; j++)
            acc[i][j] = (f32x4)(0.0f);

    for (int k0 = 0; k0 < K_DIM; k0 += BK) {
#pragma unroll
        for (int p = 0; p < 2; ++p) {
            const int seg = wave * 2 + p;   // 16-row segment index, 0..7
            glds16(A + (size_t)(rowBase + seg * 16 + dRow) * K_DIM + k0 + dCol,
                   &sA[seg * 512]);
            glds16(Bm + (size_t)(colBase + seg * 16 + dRow) * K_DIM + k0 + dCol,
                   &sB[seg * 512]);
        }
        __syncthreads();   // compiler drains vmcnt(0) here -> LDS tiles ready

        bf16x8 af[4], bfr[4];
#pragma unroll
        for (int i = 0; i < 4; i++)
            af[i] = *reinterpret_cast<const bf16x8*>(
                &sA[(wr + i * 16 + laneLo) * BK + laneHi * 8]);
#pragma unroll
        for (int j = 0; j < 4; j++)
            bfr[j] = *reinterpret_cast<const bf16x8*>(
                &sB[(wc + j * 16 + laneLo) * BK + laneHi * 8]);
        __syncthreads();   // fragments in regs; LDS free for next k-step

#pragma unroll
        for (int i = 0; i < 4; i++)
#pragma unroll
            for (int j = 0; j < 4; j++)
                acc[i][j] = __builtin_amdgcn_mfma_f32_16x16x32_bf16(
                    af[i], bfr[j], acc[i][j], 0, 0, 0);
    }

    // Epilogue. C/D layout: col = lane&15, row = (lane>>4)*4 + reg  [m89/m91]
#pragma unroll
    for (int i = 0; i < 4; i++) {
        int row = rowBase + wr + i * 16 + laneHi * 4;
#pragma unroll
        for (int j = 0; j < 4; j++) {
            int col = colBase + wc + j * 16 + laneLo;
            if (col < D_DIM) {
                float bias = b_alpha[col];
#pragma unroll
                for (int r = 0; r < 4; r++) {
                    float z = acc[i][j][r] + bias;
                    alpha_out[(size_t)(row + r) * D_DIM + col] = sigmoid_f(z);
                }
            } else {
                int c2 = col - D_DIM;
                float bias = b_x[c2];
#pragma unroll
                for (int r = 0; r < 4; r++)
                    wx_out[(size_t)(row + r) * D_DIM + c2] = acc[i][j][r] + bias;
            }
        }
    }
}

// ---------------------------------------------------------------------------
// Sequential scan, producer-consumer:
//   block = 128 thr = 2 waves. Wave 0 computes 64 channels; wave 1 DMA-stages
//   32-timestep tiles of alpha/wx into double-buffered LDS via global_load_lds.
//   One __syncthreads per tile: producer's vmcnt(0) drain overlaps consumer math.
// LDS layout per tile buffer: row-major [TT][64] fp32 (natural layout of the
// width-16 DMA: lane l -> timestep p*4 + l/16, channels (l%16)*4..+3).
//   v = tanh(h + wx); h = a*h + (1-a)*v; out = h^2*sigmoid(h); hout[t+1] = h
// ---------------------------------------------------------------------------
#define TT 32
#define NT (T_STEPS / TT)   // 64 tiles
__global__ __launch_bounds__(128)
void scan_kernel(const float* __restrict__ alpha,  // [T][NCH]
                 const float* __restrict__ wx,     // [T][NCH]
                 const float* __restrict__ h0,     // [NCH]
                 float* __restrict__ out,          // [T][NCH]
                 float* __restrict__ hout)         // [T+1][NCH]
{
    __shared__ float sAl[2][TT * 64];   // 2 x 8 KB
    __shared__ float sWx[2][TT * 64];   // 2 x 8 KB

    const int lane = threadIdx.x & 63;
    const int wave = threadIdx.x >> 6;
    const int ch0  = blockIdx.x * 64;

    float h = 0.0f;

    if (wave == 1) {
        // producer: stage tile 0 into buffer 0
        const int q  = lane >> 4;          // timestep-sub 0..3 within instr
        const int c4 = (lane & 15) * 4;    // channel group
#pragma unroll
        for (int p = 0; p < TT / 4; ++p) {
            const size_t g = (size_t)(p * 4 + q) * NCH + ch0 + c4;
            glds16(alpha + g, &sAl[0][p * 256]);
            glds16(wx    + g, &sWx[0][p * 256]);
        }
    } else {
        h = h0[ch0 + lane];
        hout[ch0 + lane] = h;
    }
    __syncthreads();   // tile 0 staged

    for (int tile = 0; tile < NT; ++tile) {
        const int cur = tile & 1;
        if (wave == 1) {
            if (tile + 1 < NT) {
                const int q  = lane >> 4;
                const int c4 = (lane & 15) * 4;
                const int t0 = (tile + 1) * TT;
#pragma unroll
                for (int p = 0; p < TT / 4; ++p) {
                    const size_t g = (size_t)(t0 + p * 4 + q) * NCH + ch0 + c4;
                    glds16(alpha + g, &sAl[cur ^ 1][p * 256]);
                    glds16(wx    + g, &sWx[cur ^ 1][p * 256]);
                }
            }
        } else {
            const int tbase = tile * TT;
#pragma unroll 8
            for (int ts = 0; ts < TT; ++ts) {
                const float a = sAl[cur][ts * 64 + lane];
                const float w = sWx[cur][ts * 64 + lane];
                const float v = tanh_f(h + w);
                h = v + a * (h - v);                  // = a*h + (1-a)*v
                const int t = tbase + ts;
                out[(size_t)t * NCH + ch0 + lane] = h * h * sigmoid_f(h);
                hout[(size_t)(t + 1) * NCH + ch0 + lane] = h;
            }
        }
        __syncthreads();   // next tile staged AND current buffer consumed
    }
}

// ---------------------------------------------------------------------------
extern "C" void kernel_launch(void* const* d_in, const int* in_sizes, int n_in,
                              void* d_out, int out_size, void* d_ws, size_t ws_size,
                              hipStream_t stream) {
    const float* x       = (const float*)d_in[0];  // [T,B,D]
    const float* h0      = (const float*)d_in[1];  // [B,D]
    const float* W_alpha = (const float*)d_in[2];  // [D,D]
    const float* b_alpha = (const float*)d_in[3];  // [D]
    const float* W_x     = (const float*)d_in[4];  // [D,D]
    const float* b       = (const float*)d_in[5];  // [D]

    float* out  = (float*)d_out;                              // [T,B,D]
    float* hout = out + (size_t)T_STEPS * BATCH * D_DIM;      // [T+1,B,D]

    // Workspace layout (~164 MB):
    //   alpha fp32 (64 MB) | wx fp32 (64 MB) | x bf16 (32 MB) | Wc bf16 (4 MB)
    float* ws_alpha = (float*)d_ws;
    float* ws_wx    = ws_alpha + (size_t)M_ROWS * D_DIM;
    unsigned short* ws_x = (unsigned short*)(ws_wx + (size_t)M_ROWS * D_DIM);
    unsigned short* ws_W = ws_x + (size_t)M_ROWS * K_DIM;

    // 1) convert x, W_alpha, W_x to bf16
    {
        int n4 = M_ROWS * K_DIM / 4;
        cvt_bf16_kernel<<<(n4 + 255) / 256, 256, 0, stream>>>(x, ws_x, n4);
    }
    {
        int n4 = D_DIM * K_DIM / 4;
        cvt_bf16_kernel<<<(n4 + 255) / 256, 256, 0, stream>>>(W_alpha, ws_W, n4);
        cvt_bf16_kernel<<<(n4 + 255) / 256, 256, 0, stream>>>(
            W_x, ws_W + (size_t)D_DIM * K_DIM, n4);
    }

    // 2) fused GEMM (N = 2048 covers both projections) + bias + sigmoid epilogue
    {
        dim3 grid(N_COLS / BN, M_ROWS / BM);   // (16, 128)
        gemm_kernel<<<grid, 256, 0, stream>>>(ws_x, ws_W, b_alpha, b,
                                              ws_alpha, ws_wx);
    }

    // 3) sequential scan: 128 blocks x (1 compute wave + 1 DMA wave)
    scan_kernel<<<NCH / 64, 128, 0, stream>>>(ws_alpha, ws_wx, h0, out, hout);
}